// Round 6
// baseline (68.631 us; speedup 1.0000x reference)
//
#include <hip/hip_runtime.h>

// out = ((x@W1.T+b1)@W2.T+b2)@W3.T+b3 ; exilu == identity (tautological mask)
// => single affine map: out = x @ Wc.T + bc, Wc = W3@W2@W1 [6,6], bc [6].
// B = 8388608 rows x 6 fp32, 201 MB in + 201 MB out.
//
// R4 evidence: NT stores stop LLC write-allocation thrash (FETCH 201->98 MB,
// 88.7->68.4 us). R5 fixes measured residuals: (a) the XOR swizzle CAUSED
// 3.67M bank conflicts -- stride-3 f32x4 LDS access is naturally conflict-free
// (3t mod 8 bijective per 8 lanes), so no swizzle; (b) 24 KB LDS capped
// occupancy at 6 blocks/CU -- single 12 KB buffer + grid 2048 = 8 blocks/CU.

typedef float f32x4 __attribute__((ext_vector_type(4)));

// ---- fold kernel: Wc = W3@W2@W1 (6x6) -> ws[0..35], bc -> ws[36..41] ----
// Separate kernel so main-kernel weights come via uniform s_loads (SGPRs,
// VGPR=40 in R3/R4) -> 8 blocks/CU fits the VGPR budget.
__global__ void fold_weights(const float* __restrict__ W1, const float* __restrict__ b1,
                             const float* __restrict__ W2, const float* __restrict__ b2,
                             const float* __restrict__ W3, const float* __restrict__ b3,
                             float* __restrict__ ws) {
    if (threadIdx.x != 0 || blockIdx.x != 0) return;
    float T1[8][6];
    for (int o = 0; o < 8; ++o)
        for (int i = 0; i < 6; ++i) {
            float s = 0.f;
            for (int k = 0; k < 8; ++k) s = fmaf(W2[o * 8 + k], W1[k * 6 + i], s);
            T1[o][i] = s;
        }
    for (int o = 0; o < 6; ++o)
        for (int i = 0; i < 6; ++i) {
            float s = 0.f;
            for (int k = 0; k < 8; ++k) s = fmaf(W3[o * 8 + k], T1[k][i], s);
            ws[o * 6 + i] = s;
        }
    float bb[8];
    for (int o = 0; o < 8; ++o) {
        float s = b2[o];
        for (int k = 0; k < 8; ++k) s = fmaf(W2[o * 8 + k], b1[k], s);
        bb[o] = s;
    }
    for (int o = 0; o < 6; ++o) {
        float s = b3[o];
        for (int k = 0; k < 8; ++k) s = fmaf(W3[o * 8 + k], bb[k], s);
        ws[36 + o] = s;
    }
}

// ---- main kernel: 512 rows (768 f32x4) per block-iteration ----
__global__ void __launch_bounds__(256) mlp_stream(const float* __restrict__ x,
                                                  const float* __restrict__ wc,
                                                  float* __restrict__ out,
                                                  int nbi) {
    __shared__ f32x4 L[768];  // 12 KB single buffer -> 8 blocks/CU

    // weights: uniform constant-offset loads -> SGPRs
    float w[6][6], bs[6];
#pragma unroll
    for (int r = 0; r < 6; ++r) {
#pragma unroll
        for (int i = 0; i < 6; ++i) w[r][i] = wc[r * 6 + i];
        bs[r] = wc[36 + r];
    }

    const int t = threadIdx.x;
    const f32x4* __restrict__ xv = reinterpret_cast<const f32x4*>(x);
    f32x4* __restrict__       ov = reinterpret_cast<f32x4*>(out);

    int bi = blockIdx.x;
    f32x4 c0, c1, c2;
    if (bi < nbi) {
        const int base = bi * 768;
        c0 = xv[base + t];
        c1 = xv[base + t + 256];
        c2 = xv[base + t + 512];
    }

    for (; bi < nbi; bi += gridDim.x) {
        // stage current tile (stride-1: conflict-free)
        L[t]       = c0;
        L[t + 256] = c1;
        L[t + 512] = c2;

        // prefetch next tile into registers (in flight across the whole iter)
        const int nb = bi + gridDim.x;
        if (nb < nbi) {
            const int nbase = nb * 768;
            c0 = xv[nbase + t];
            c1 = xv[nbase + t + 256];
            c2 = xv[nbase + t + 512];
        }

        __syncthreads();  // b1: stage visible

        // own rows 2t, 2t+1 = f32x4 {3t, 3t+1, 3t+2} (stride-3: conflict-free)
        const f32x4 a = L[3 * t];
        const f32x4 b = L[3 * t + 1];
        const f32x4 c = L[3 * t + 2];
        const float xin[12] = {a.x, a.y, a.z, a.w, b.x, b.y,
                               b.z, b.w, c.x, c.y, c.z, c.w};
        float o[12];
#pragma unroll
        for (int r = 0; r < 2; ++r) {
#pragma unroll
            for (int j = 0; j < 6; ++j) {
                float s = bs[j];
#pragma unroll
                for (int i = 0; i < 6; ++i) s = fmaf(w[j][i], xin[6 * r + i], s);
                o[6 * r + j] = s;
            }
        }
        // write back into the SAME slots this thread read -> no extra barrier
        L[3 * t]     = (f32x4){o[0], o[1], o[2],  o[3]};
        L[3 * t + 1] = (f32x4){o[4], o[5], o[6],  o[7]};
        L[3 * t + 2] = (f32x4){o[8], o[9], o[10], o[11]};

        __syncthreads();  // b2: results visible

        const int base = bi * 768;
        // NT stores: no LLC allocation -> keep x LLC-resident across replays.
        __builtin_nontemporal_store(L[t],       &ov[base + t]);
        __builtin_nontemporal_store(L[t + 256], &ov[base + t + 256]);
        __builtin_nontemporal_store(L[t + 512], &ov[base + t + 512]);

        __syncthreads();  // b3: output reads done before next stage overwrites
    }
}

extern "C" void kernel_launch(void* const* d_in, const int* in_sizes, int n_in,
                              void* d_out, int out_size, void* d_ws, size_t ws_size,
                              hipStream_t stream) {
    const float* x  = (const float*)d_in[0];
    const float* W1 = (const float*)d_in[1];
    const float* b1 = (const float*)d_in[2];
    const float* W2 = (const float*)d_in[3];
    const float* b2 = (const float*)d_in[4];
    const float* W3 = (const float*)d_in[5];
    const float* b3 = (const float*)d_in[6];
    float* outp = (float*)d_out;
    float* ws   = (float*)d_ws;

    fold_weights<<<1, 64, 0, stream>>>(W1, b1, W2, b2, W3, b3, ws);

    // 50331648 floats / 3072 floats-per-block-iter = 16384 block-iters
    int nbi = in_sizes[0] / 3072;
    int blocks = 2048;  // 8 blocks/CU, exactly 8 iterations per block
    mlp_stream<<<blocks, 256, 0, stream>>>(x, ws, outp, nbi);
}

// Round 7
// 65.701 us; speedup vs baseline: 1.0446x; 1.0446x over previous
//
#include <hip/hip_runtime.h>

// out = ((x@W1.T+b1)@W2.T+b2)@W3.T+b3 ; exilu == identity (tautological mask)
// => single affine map: out = x @ Wc.T + bc, Wc = W3@W2@W1 [6,6], bc [6].
// B = 8388608 rows x 6 fp32, 201 MB in + 201 MB out.
//
// Ledger: R4 NT stores (LLC write-thrash fix): 88.7->68.4 us, FETCH 201->98 MB.
// R5 (conflicts->0, occupancy 48->61%): neutral -> not LDS/occupancy-bound.
// Main kernel runs at ~6.1 TB/s logical = 97% of the m13 copy ceiling.
// R6: fuse the weight fold per-thread -> single dispatch (remove the serial
// fold kernel + graph dispatch boundary, ~3-4 us). Weights move SGPR->VGPR;
// R5 proved occupancy headroom makes that free.

typedef float f32x4 __attribute__((ext_vector_type(4)));

__global__ void __launch_bounds__(256) mlp_one(const float* __restrict__ x,
                                               const float* __restrict__ W1,
                                               const float* __restrict__ b1,
                                               const float* __restrict__ W2,
                                               const float* __restrict__ b2,
                                               const float* __restrict__ W3,
                                               const float* __restrict__ b3,
                                               float* __restrict__ out,
                                               int nbi) {
    __shared__ f32x4 L[768];  // 12 KB single buffer

    const int t = threadIdx.x;
    const f32x4* __restrict__ xv = reinterpret_cast<const f32x4*>(x);
    f32x4* __restrict__       ov = reinterpret_cast<f32x4*>(out);

    // ---- issue first tile's loads BEFORE the fold so HBM starts now ----
    int bi = blockIdx.x;
    f32x4 c0, c1, c2;
    if (bi < nbi) {
        const int base = bi * 768;
        c0 = xv[base + t];
        c1 = xv[base + t + 256];
        c2 = xv[base + t + 512];
    }

    // ---- per-thread fold: Wc = W3@(W2@W1), bc = W3@(W2@b1+b2)+b3 ----
    // ~780 FMAs, one-time; hides under the memory stream (VALUBusy ~5%).
    float T1[8][6];
#pragma unroll
    for (int o = 0; o < 8; ++o)
#pragma unroll
        for (int i = 0; i < 6; ++i) {
            float s = 0.f;
#pragma unroll
            for (int k = 0; k < 8; ++k) s = fmaf(W2[o * 8 + k], W1[k * 6 + i], s);
            T1[o][i] = s;
        }
    float w[6][6], bs[6];
#pragma unroll
    for (int o = 0; o < 6; ++o)
#pragma unroll
        for (int i = 0; i < 6; ++i) {
            float s = 0.f;
#pragma unroll
            for (int k = 0; k < 8; ++k) s = fmaf(W3[o * 8 + k], T1[k][i], s);
            w[o][i] = s;
        }
    {
        float bb[8];
#pragma unroll
        for (int o = 0; o < 8; ++o) {
            float s = b2[o];
#pragma unroll
            for (int k = 0; k < 8; ++k) s = fmaf(W2[o * 8 + k], b1[k], s);
            bb[o] = s;
        }
#pragma unroll
        for (int o = 0; o < 6; ++o) {
            float s = b3[o];
#pragma unroll
            for (int k = 0; k < 8; ++k) s = fmaf(W3[o * 8 + k], bb[k], s);
            bs[o] = s;
        }
    }

    // ---- stream loop (identical to R5) ----
    for (; bi < nbi; bi += gridDim.x) {
        L[t]       = c0;
        L[t + 256] = c1;
        L[t + 512] = c2;

        const int nb = bi + gridDim.x;
        if (nb < nbi) {
            const int nbase = nb * 768;
            c0 = xv[nbase + t];
            c1 = xv[nbase + t + 256];
            c2 = xv[nbase + t + 512];
        }

        __syncthreads();  // stage visible

        const f32x4 a = L[3 * t];
        const f32x4 b = L[3 * t + 1];
        const f32x4 c = L[3 * t + 2];
        const float xin[12] = {a.x, a.y, a.z, a.w, b.x, b.y,
                               b.z, b.w, c.x, c.y, c.z, c.w};
        float o[12];
#pragma unroll
        for (int r = 0; r < 2; ++r) {
#pragma unroll
            for (int j = 0; j < 6; ++j) {
                float s = bs[j];
#pragma unroll
                for (int i = 0; i < 6; ++i) s = fmaf(w[j][i], xin[6 * r + i], s);
                o[6 * r + j] = s;
            }
        }
        L[3 * t]     = (f32x4){o[0], o[1], o[2],  o[3]};
        L[3 * t + 1] = (f32x4){o[4], o[5], o[6],  o[7]};
        L[3 * t + 2] = (f32x4){o[8], o[9], o[10], o[11]};

        __syncthreads();  // results visible

        const int base = bi * 768;
        __builtin_nontemporal_store(L[t],       &ov[base + t]);
        __builtin_nontemporal_store(L[t + 256], &ov[base + t + 256]);
        __builtin_nontemporal_store(L[t + 512], &ov[base + t + 512]);

        __syncthreads();  // output reads done before next stage overwrites
    }
}

extern "C" void kernel_launch(void* const* d_in, const int* in_sizes, int n_in,
                              void* d_out, int out_size, void* d_ws, size_t ws_size,
                              hipStream_t stream) {
    const float* x  = (const float*)d_in[0];
    const float* W1 = (const float*)d_in[1];
    const float* b1 = (const float*)d_in[2];
    const float* W2 = (const float*)d_in[3];
    const float* b2 = (const float*)d_in[4];
    const float* W3 = (const float*)d_in[5];
    const float* b3 = (const float*)d_in[6];
    float* outp = (float*)d_out;

    // 50331648 floats / 3072 floats-per-block-iter = 16384 block-iters
    int nbi = in_sizes[0] / 3072;
    int blocks = 2048;  // exactly 8 iterations per block
    mlp_one<<<blocks, 256, 0, stream>>>(x, W1, b1, W2, b2, W3, b3, outp, nbi);
}